// Round 4
// baseline (851.071 us; speedup 1.0000x reference)
//
#include <hip/hip_runtime.h>
#include <math.h>

// Problem constants (from reference)
#define BATCH 16384
#define PP    208      // ids per row (26 features * 8 slots)
#define NF    26       // feature categories
#define VPF   50000u   // vocab per feature
#define EMB   32       // embed dim
#define DD    832      // NF * EMB
#define VOCAB (NF * 50000)

// Slice sweep parameters: slice = id >> 14 (16384 vocab rows = 1 MB bf16)
#define SLSH  14
#define NS    80       // ceil(1.3e6 / 16384)

typedef __attribute__((ext_vector_type(8))) short short8v;   // 8 bf16
typedef __attribute__((ext_vector_type(4))) float float4v;   // MFMA C/D frag

static __device__ __forceinline__ ushort f32_to_bf16(float f) {
    unsigned u = __builtin_bit_cast(unsigned, f);
    unsigned r = (u + 0x7fffu + ((u >> 16) & 1u)) >> 16;   // RNE
    return (ushort)r;
}
static __device__ __forceinline__ unsigned pack_bf16x2(float lo, float hi) {
    return (unsigned)f32_to_bf16(lo) | ((unsigned)f32_to_bf16(hi) << 16);
}

// ---------------------------------------------------------------------------
// Kernel T: f32 table -> bf16 table (83 MB), streaming.
// ---------------------------------------------------------------------------
__global__ __launch_bounds__(256) void prep_tbl(const float* __restrict__ table,
                                                ushort* __restrict__ tbl16) {
    const size_t i = ((size_t)blockIdx.x * 256 + threadIdx.x) * 8;
    if (i >= (size_t)VOCAB * EMB) return;
    const float4 a = *reinterpret_cast<const float4*>(table + i);
    const float4 b = *reinterpret_cast<const float4*>(table + i + 4);
    uint4 o;
    o.x = pack_bf16x2(a.x, a.y);
    o.y = pack_bf16x2(a.z, a.w);
    o.z = pack_bf16x2(b.x, b.y);
    o.w = pack_bf16x2(b.z, b.w);
    *reinterpret_cast<uint4*>(tbl16 + i) = o;
}

// ---------------------------------------------------------------------------
// Kernel P: pre-pack W0 -> bf16 fragment order (verified R2/R3):
//   w0p[(kt*64 + col)*32 + kk], k = kt*32 + kk
// ---------------------------------------------------------------------------
__global__ __launch_bounds__(256) void prep_w0(const float* __restrict__ W0,
                                               ushort* __restrict__ w0p) {
    const int i = blockIdx.x * 256 + threadIdx.x;
    if (i < DD * 64) {
        const int k = i >> 6, c = i & 63;
        const int kt = k >> 5, kk = k & 31;
        w0p[(kt * 64 + c) * 32 + kk] = f32_to_bf16(W0[i]);
    }
}

// ---------------------------------------------------------------------------
// Kernel S: per-row counting sort of the 208 ids by table slice (id>>14).
// Writes sorted ids [BATCH][208] and slice offsets [BATCH][NS+1] (ushort).
// ---------------------------------------------------------------------------
__global__ __launch_bounds__(256) void sort_prep(const int* __restrict__ x,
                                                 int* __restrict__ sorted,
                                                 ushort* __restrict__ offs) {
    __shared__ int s_id[PP];
    __shared__ int s_cnt[NS];
    __shared__ int s_base[NS + 1];

    const int    tid = threadIdx.x;
    const size_t row = blockIdx.x;

    if (tid < PP / 4)
        reinterpret_cast<int4*>(s_id)[tid] =
            reinterpret_cast<const int4*>(x + row * PP)[tid];
    if (tid < NS) s_cnt[tid] = 0;
    __syncthreads();

    if (tid < PP) atomicAdd(&s_cnt[((unsigned)s_id[tid]) >> SLSH], 1);
    __syncthreads();

    if (tid == 0) {
        int acc = 0;
        for (int s = 0; s < NS; ++s) { s_base[s] = acc; acc += s_cnt[s]; }
        s_base[NS] = acc;   // == PP
    }
    __syncthreads();

    if (tid < NS) s_cnt[tid] = s_base[tid];   // next-index per slice
    if (tid <= NS) offs[row * (NS + 1) + tid] = (ushort)s_base[tid];
    __syncthreads();

    if (tid < PP) {
        const int id  = s_id[tid];
        const int pos = atomicAdd(&s_cnt[((unsigned)id) >> SLSH], 1);
        sorted[row * PP + pos] = id;
    }
}

// ---------------------------------------------------------------------------
// Kernel A (tier 1): slice-swept gather + segment sum. 8 rows per block,
// grid 2048 (~all resident -> soft-lockstep slice sweep -> L2-resident
// slice). 256 threads = 16 groups of 16 lanes; group g -> (row g>>1,
// half g&1); lane l covers dims 2l,2l+1 (ushort2 of a 64B bf16 row).
// ---------------------------------------------------------------------------
__global__ __launch_bounds__(256) void pool_sweep(const int* __restrict__ sorted,
                                                  const ushort* __restrict__ offs,
                                                  const ushort* __restrict__ tbl,
                                                  ushort* __restrict__ feats) {
    __shared__ float  s_pool[8 * DD];         // 26.6 KB
    __shared__ ushort s_off[8 * (NS + 1)];    // 1.3 KB

    const int tid  = threadIdx.x;
    const int row0 = blockIdx.x * 8;

    for (int i = tid; i < 8 * DD; i += 256) s_pool[i] = 0.0f;
    for (int i = tid; i < 8 * (NS + 1); i += 256) {
        const int r = i / (NS + 1), s = i - r * (NS + 1);
        s_off[i] = offs[(size_t)(row0 + r) * (NS + 1) + s];
    }
    __syncthreads();

    const int g = tid >> 4;     // group 0..15
    const int l = tid & 15;     // dim pair
    const int r = g >> 1;       // row 0..7
    const int h = g & 1;        // half

    const ushort* offr = s_off + r * (NS + 1);
    float*        pool = s_pool + r * DD + 2 * l;
    const int*    srow = sorted + (size_t)(row0 + r) * PP;

    for (int s = 0; s < NS; ++s) {
        const int e = offr[s + 1];
        for (int j = offr[s] + h; j < e; j += 2) {
            const unsigned id = (unsigned)srow[j];   // broadcast within group
            const unsigned v  = *reinterpret_cast<const unsigned*>(
                                    tbl + (size_t)id * EMB + 2 * l);
            const unsigned cat = id / VPF;
            atomicAdd(pool + cat * EMB + 0, __builtin_bit_cast(float, v << 16));
            atomicAdd(pool + cat * EMB + 1, __builtin_bit_cast(float, v & 0xffff0000u));
        }
    }
    __syncthreads();

    for (int i = tid; i < 8 * DD / 4; i += 256) {
        ushort4 o;
        o.x = f32_to_bf16(s_pool[i * 4 + 0]);
        o.y = f32_to_bf16(s_pool[i * 4 + 1]);
        o.z = f32_to_bf16(s_pool[i * 4 + 2]);
        o.w = f32_to_bf16(s_pool[i * 4 + 3]);
        *reinterpret_cast<ushort4*>(feats + (size_t)row0 * DD + i * 4) = o;
    }
}

// ---------------------------------------------------------------------------
// Kernel A (tier 2): unsorted bf16 gather (R3 pool, proven).
// ---------------------------------------------------------------------------
__global__ __launch_bounds__(256, 4) void pool_bf16(const int* __restrict__ x,
                                                    const ushort* __restrict__ tbl,
                                                    ushort* __restrict__ feats) {
    __shared__ int   s_ids[PP];
    __shared__ float s_pool[DD];

    const int    tid = threadIdx.x;
    const size_t row = blockIdx.x;

    for (int i = tid; i < DD; i += 256) s_pool[i] = 0.0f;
    if (tid < PP / 4)
        reinterpret_cast<int4*>(s_ids)[tid] =
            reinterpret_cast<const int4*>(x + row * PP)[tid];
    __syncthreads();

    const int g = tid >> 4;
    const int l = tid & 15;

    unsigned ids[13];
#pragma unroll
    for (int p = 0; p < 13; ++p) ids[p] = (unsigned)s_ids[p * 16 + g];
    unsigned vals[13];
#pragma unroll
    for (int p = 0; p < 13; ++p)
        vals[p] = *reinterpret_cast<const unsigned*>(tbl + (size_t)ids[p] * EMB + 2 * l);

    float* pool = s_pool + 2 * l;
#pragma unroll
    for (int p = 0; p < 13; ++p) {
        const unsigned cat = ids[p] / VPF;
        atomicAdd(pool + cat * EMB + 0, __builtin_bit_cast(float, vals[p] << 16));
        atomicAdd(pool + cat * EMB + 1, __builtin_bit_cast(float, vals[p] & 0xffff0000u));
    }
    __syncthreads();

    if (tid < DD / 4) {
        ushort4 o;
        o.x = f32_to_bf16(s_pool[tid * 4 + 0]);
        o.y = f32_to_bf16(s_pool[tid * 4 + 1]);
        o.z = f32_to_bf16(s_pool[tid * 4 + 2]);
        o.w = f32_to_bf16(s_pool[tid * 4 + 3]);
        *reinterpret_cast<ushort4*>(feats + row * DD + tid * 4) = o;
    }
}

// ---------------------------------------------------------------------------
// Kernel A (tier 3): f32-table gather (R2 pool, proven).
// ---------------------------------------------------------------------------
__global__ __launch_bounds__(256, 4) void pool_f32(const int* __restrict__ x,
                                                   const float* __restrict__ table,
                                                   ushort* __restrict__ feats) {
    __shared__ int   s_ids[PP];
    __shared__ float s_pool[DD];

    const int    tid = threadIdx.x;
    const size_t row = blockIdx.x;

    for (int i = tid; i < DD; i += 256) s_pool[i] = 0.0f;
    if (tid < PP / 4)
        reinterpret_cast<int4*>(s_ids)[tid] =
            reinterpret_cast<const int4*>(x + row * PP)[tid];
    __syncthreads();

    const int e  = tid & 31;
    const int p0 = (tid >> 5) * 26;
    float* pool  = s_pool + e;

#pragma unroll 1
    for (int b = 0; b < 26; b += 2) {
        const unsigned id0 = (unsigned)s_ids[p0 + b + 0];
        const unsigned id1 = (unsigned)s_ids[p0 + b + 1];
        const float v0 = table[(size_t)id0 * EMB + e];
        const float v1 = table[(size_t)id1 * EMB + e];
        atomicAdd(pool + (id0 / VPF) * EMB, v0);
        atomicAdd(pool + (id1 / VPF) * EMB, v1);
    }
    __syncthreads();

    if (tid < DD / 4) {
        ushort4 o;
        o.x = f32_to_bf16(s_pool[tid * 4 + 0]);
        o.y = f32_to_bf16(s_pool[tid * 4 + 1]);
        o.z = f32_to_bf16(s_pool[tid * 4 + 2]);
        o.w = f32_to_bf16(s_pool[tid * 4 + 3]);
        *reinterpret_cast<ushort4*>(feats + row * DD + tid * 4) = o;
    }
}

// ---------------------------------------------------------------------------
// Kernel B: MFMA MLP. Grid 1024 x 256 thr (4 blocks/CU, 16 waves/CU).
// Block = 16 rows; wave w owns cols [16w,16w+16), full K (26 kt steps).
// Frag layout (R2/R3-verified): A row=lane&15, k=(lane>>4)*8+j;
// B col=lane&15; C row=(lane>>4)*4+reg, col=lane&15.
// ---------------------------------------------------------------------------
__global__ __launch_bounds__(256) void mlp_kernel(const ushort* __restrict__ feats,
                                                  const ushort* __restrict__ w0p,
                                                  const float* __restrict__ b0,
                                                  const float* __restrict__ W1,
                                                  const float* __restrict__ b1,
                                                  const float* __restrict__ W2,
                                                  float* __restrict__ out) {
    __shared__ float sH[16][65];
    __shared__ float sH1[16][17];

    const int tid   = threadIdx.x;
    const int w     = tid >> 6;
    const int lane  = tid & 63;
    const int lrow  = lane & 15;
    const int lk    = lane >> 4;
    const int brow0 = blockIdx.x * 16;

    float4v acc = (float4v){0.f, 0.f, 0.f, 0.f};

    const ushort* frow  = feats + (size_t)(brow0 + lrow) * DD + lk * 8;
    const ushort* wbase = w0p + (size_t)(w * 16 + lrow) * 32 + lk * 8;

#pragma unroll 2
    for (int kt = 0; kt < 26; ++kt) {
        const short8v a = *reinterpret_cast<const short8v*>(frow + kt * 32);
        const short8v b = *reinterpret_cast<const short8v*>(wbase + (size_t)kt * 64 * 32);
        acc = __builtin_amdgcn_mfma_f32_16x16x32_bf16(a, b, acc, 0, 0, 0);
    }

    {
        const int   col = w * 16 + lrow;
        const float bb  = b0[col];
#pragma unroll
        for (int r = 0; r < 4; ++r)
            sH[lk * 4 + r][col] = fmaxf(acc[r] + bb, 0.f);
    }
    __syncthreads();

    {   // h1[r][c] = relu(b1[c] + sum_k sH[r][k] * W1[k][c])
        const int r = tid >> 4, c = tid & 15;
        float a0 = b1[c];
#pragma unroll 8
        for (int k = 0; k < 64; ++k)
            a0 = fmaf(sH[r][k], W1[k * 16 + c], a0);
        sH1[r][c] = fmaxf(a0, 0.f);
    }
    __syncthreads();

    if (tid < 16) {
        float z = 0.f;
#pragma unroll
        for (int j = 0; j < 16; ++j) z = fmaf(sH1[tid][j], W2[j], z);
        out[brow0 + tid] = 1.f / (1.f + expf(-z));
    }
}

extern "C" void kernel_launch(void* const* d_in, const int* in_sizes, int n_in,
                              void* d_out, int out_size, void* d_ws, size_t ws_size,
                              hipStream_t stream) {
    const int*   x     = (const int*)d_in[0];
    const float* table = (const float*)d_in[1];
    const float* W0    = (const float*)d_in[2];
    const float* b0    = (const float*)d_in[3];
    const float* W1    = (const float*)d_in[4];
    const float* b1    = (const float*)d_in[5];
    const float* W2    = (const float*)d_in[6];
    float*       out   = (float*)d_out;

    // ws layout
    ushort* feats16 = (ushort*)d_ws;                                   // 27.3 MB
    ushort* w0p     = feats16 + (size_t)BATCH * DD;                    // 106 KB
    ushort* tbl16   = w0p + (size_t)DD * 64;                           // 83.2 MB
    int*    sorted  = (int*)(tbl16 + (size_t)VOCAB * EMB);             // 13.6 MB
    ushort* offs    = (ushort*)(sorted + (size_t)BATCH * PP);          // 2.65 MB

    const size_t need_t2 = ((size_t)BATCH * DD + (size_t)DD * 64 + (size_t)VOCAB * EMB) * 2;
    const size_t need_t1 = need_t2 + (size_t)BATCH * PP * 4 + (size_t)BATCH * (NS + 1) * 2;

    prep_w0<<<(DD * 64 + 255) / 256, 256, 0, stream>>>(W0, w0p);

    if (ws_size >= need_t1) {
        const int nconv = ((int)((size_t)VOCAB * EMB / 8) + 255) / 256;
        prep_tbl<<<nconv, 256, 0, stream>>>(table, tbl16);
        sort_prep<<<BATCH, 256, 0, stream>>>(x, sorted, offs);
        pool_sweep<<<BATCH / 8, 256, 0, stream>>>(sorted, offs, tbl16, feats16);
    } else if (ws_size >= need_t2) {
        const int nconv = ((int)((size_t)VOCAB * EMB / 8) + 255) / 256;
        prep_tbl<<<nconv, 256, 0, stream>>>(table, tbl16);
        pool_bf16<<<BATCH, 256, 0, stream>>>(x, tbl16, feats16);
    } else {
        pool_f32<<<BATCH, 256, 0, stream>>>(x, table, feats16);
    }

    mlp_kernel<<<BATCH / 16, 256, 0, stream>>>(feats16, w0p, b0, W1, b1, W2, out);
}

// Round 5
// 744.247 us; speedup vs baseline: 1.1435x; 1.1435x over previous
//
#include <hip/hip_runtime.h>
#include <math.h>

// Problem constants (from reference)
#define BATCH 16384
#define PP    208      // ids per row (26 features * 8 slots)
#define NF    26       // feature categories
#define VPF   50000u   // vocab per feature
#define EMB   32       // embed dim
#define DD    832      // NF * EMB
#define VOCAB (NF * 50000)

typedef __attribute__((ext_vector_type(8))) short short8v;   // 8 bf16
typedef __attribute__((ext_vector_type(4))) float float4v;   // MFMA C/D frag

static __device__ __forceinline__ ushort f32_to_bf16(float f) {
    unsigned u = __builtin_bit_cast(unsigned, f);
    unsigned r = (u + 0x7fffu + ((u >> 16) & 1u)) >> 16;   // RNE
    return (ushort)r;
}
static __device__ __forceinline__ unsigned pack_bf16x2(float lo, float hi) {
    return (unsigned)f32_to_bf16(lo) | ((unsigned)f32_to_bf16(hi) << 16);
}

// ---------------------------------------------------------------------------
// Fragment layouts (R2/R3-verified MFMA 16x16x32 bf16 mapping):
//   A: row = lane&15, k = (lane>>4)*8 + j      (per 32-wide kt block)
//   B: col = lane&15, same k
//   C: row = (lane>>4)*4 + reg, col = lane&15
//
// feats_frag[ ((rb*26 + kt)*64 + lane) * 8 + j ]
//     = feats[rb*16 + (lane&15)][kt*32 + (lane>>4)*8 + j]     (bf16)
// w0p_frag [ ((kt*4 + w)*64 + lane) * 8 + j ]
//     = W0[kt*32 + (lane>>4)*8 + j][w*16 + (lane&15)]         (bf16)
// => every wave A/B fragment load is 1KB fully contiguous.
// ---------------------------------------------------------------------------

// Kernel P: pre-pack W0 -> bf16 fragment order (sequential writes).
__global__ __launch_bounds__(256) void prep_w0(const float* __restrict__ W0,
                                               ushort* __restrict__ w0p) {
    const int i = blockIdx.x * 256 + threadIdx.x;
    if (i < DD * 64) {
        const int j    = i & 7;
        const int lane = (i >> 3) & 63;
        const int w    = (i >> 9) & 3;
        const int kt   = i >> 11;
        const int k    = kt * 32 + (lane >> 4) * 8 + j;
        const int col  = w * 16 + (lane & 15);
        w0p[i] = f32_to_bf16(W0[(size_t)k * 64 + col]);
    }
}

// ---------------------------------------------------------------------------
// Kernel A: gather + per-category segment sum (R2-proven structure: one row
// per block, 8 chunks x 32 dims, 2-deep load batches). New: epilogue emits
// feats in MFMA fragment order (104 x 16B scattered stores — write-side,
// latency-free).
// ---------------------------------------------------------------------------
__global__ __launch_bounds__(256, 4) void pool_f32(const int* __restrict__ x,
                                                   const float* __restrict__ table,
                                                   ushort* __restrict__ featsw) {
    __shared__ int   s_ids[PP];
    __shared__ float s_pool[DD];

    const int    tid = threadIdx.x;
    const size_t row = blockIdx.x;

    for (int i = tid; i < DD; i += 256) s_pool[i] = 0.0f;
    if (tid < PP / 4)
        reinterpret_cast<int4*>(s_ids)[tid] =
            reinterpret_cast<const int4*>(x + row * PP)[tid];
    __syncthreads();

    const int e  = tid & 31;
    const int p0 = (tid >> 5) * 26;
    float* pool  = s_pool + e;

#pragma unroll 1
    for (int b = 0; b < 26; b += 2) {
        const unsigned id0 = (unsigned)s_ids[p0 + b + 0];
        const unsigned id1 = (unsigned)s_ids[p0 + b + 1];
        const float v0 = table[(size_t)id0 * EMB + e];
        const float v1 = table[(size_t)id1 * EMB + e];
        atomicAdd(pool + (id0 / VPF) * EMB, v0);
        atomicAdd(pool + (id1 / VPF) * EMB, v1);
    }
    __syncthreads();

    // Emit fragment-ordered bf16 feats: thread (tid<104) -> (kt, lk) chunk.
    if (tid < 104) {
        const int kt = tid >> 2;
        const int lk = tid & 3;
        const float* s = s_pool + kt * 32 + lk * 8;
        uint4 o;
        o.x = pack_bf16x2(s[0], s[1]);
        o.y = pack_bf16x2(s[2], s[3]);
        o.z = pack_bf16x2(s[4], s[5]);
        o.w = pack_bf16x2(s[6], s[7]);
        const size_t rb = row >> 4, lr = row & 15;
        ushort* dst = featsw + (((rb * 26 + kt) * 64) + lk * 16 + lr) * 8;
        *reinterpret_cast<uint4*>(dst) = o;
    }
}

// ---------------------------------------------------------------------------
// Kernel B: MFMA MLP on fragment-ordered inputs. Grid 1024 x 256 thr
// (4 blocks/CU). Block = 16 rows (rb); wave w owns cols [16w,16w+16).
// Every A/B load is a contiguous 1KB wave burst. Two acc chains break the
// 26-deep MFMA dependency.
// ---------------------------------------------------------------------------
__global__ __launch_bounds__(256) void mlp_kernel(const ushort* __restrict__ featsw,
                                                  const ushort* __restrict__ w0p,
                                                  const float* __restrict__ b0,
                                                  const float* __restrict__ W1,
                                                  const float* __restrict__ b1,
                                                  const float* __restrict__ W2,
                                                  float* __restrict__ out) {
    __shared__ float sH[16][65];
    __shared__ float sH1[16][17];

    const int tid  = threadIdx.x;
    const int w    = tid >> 6;
    const int lane = tid & 63;
    const int rb   = blockIdx.x;

    const ushort* A = featsw + ((size_t)rb * 26 * 64 + lane) * 8;
    const ushort* B = w0p + (size_t)(w * 64 + lane) * 8;

    float4v acc0 = (float4v){0.f, 0.f, 0.f, 0.f};
    float4v acc1 = (float4v){0.f, 0.f, 0.f, 0.f};

#pragma unroll
    for (int kt = 0; kt < 26; kt += 2) {
        const short8v a0 = *reinterpret_cast<const short8v*>(A + (size_t)kt * 512);
        const short8v b0v = *reinterpret_cast<const short8v*>(B + (size_t)kt * 2048);
        const short8v a1 = *reinterpret_cast<const short8v*>(A + (size_t)(kt + 1) * 512);
        const short8v b1v = *reinterpret_cast<const short8v*>(B + (size_t)(kt + 1) * 2048);
        acc0 = __builtin_amdgcn_mfma_f32_16x16x32_bf16(a0, b0v, acc0, 0, 0, 0);
        acc1 = __builtin_amdgcn_mfma_f32_16x16x32_bf16(a1, b1v, acc1, 0, 0, 0);
    }

    {
        const int   col = w * 16 + (lane & 15);
        const float bb  = b0[col];
#pragma unroll
        for (int r = 0; r < 4; ++r) {
            const int rr = (lane >> 4) * 4 + r;
            sH[rr][col] = fmaxf(acc0[r] + acc1[r] + bb, 0.f);
        }
    }
    __syncthreads();

    {   // h1[r][c] = relu(b1[c] + sum_k sH[r][k] * W1[k][c])
        const int r = tid >> 4, c = tid & 15;
        float a0 = b1[c];
#pragma unroll 8
        for (int k = 0; k < 64; ++k)
            a0 = fmaf(sH[r][k], W1[k * 16 + c], a0);
        sH1[r][c] = fmaxf(a0, 0.f);
    }
    __syncthreads();

    if (tid < 16) {
        float z = 0.f;
#pragma unroll
        for (int j = 0; j < 16; ++j) z = fmaf(sH1[tid][j], W2[j], z);
        out[(size_t)rb * 16 + tid] = 1.f / (1.f + expf(-z));
    }
}

extern "C" void kernel_launch(void* const* d_in, const int* in_sizes, int n_in,
                              void* d_out, int out_size, void* d_ws, size_t ws_size,
                              hipStream_t stream) {
    const int*   x     = (const int*)d_in[0];
    const float* table = (const float*)d_in[1];
    const float* W0    = (const float*)d_in[2];
    const float* b0    = (const float*)d_in[3];
    const float* W1    = (const float*)d_in[4];
    const float* b1    = (const float*)d_in[5];
    const float* W2    = (const float*)d_in[6];
    float*       out   = (float*)d_out;

    // ws layout: feats_frag 27.3 MB + w0p_frag 106 KB
    ushort* featsw = (ushort*)d_ws;
    ushort* w0p    = featsw + (size_t)BATCH * DD;

    prep_w0<<<(DD * 64 + 255) / 256, 256, 0, stream>>>(W0, w0p);
    pool_f32<<<BATCH, 256, 0, stream>>>(x, table, featsw);
    mlp_kernel<<<BATCH / 16, 256, 0, stream>>>(featsw, w0p, b0, W1, b1, W2, out);
}